// Round 1
// baseline (2396.719 us; speedup 1.0000x reference)
//
#include <hip/hip_runtime.h>
#include <hip/hip_bf16.h>
#include <cstdint>

typedef unsigned short u16;
typedef __attribute__((ext_vector_type(8))) short bf16x8;   // 8 bf16 = 4 VGPRs (MFMA A/B frag)
typedef __attribute__((ext_vector_type(8))) u16  u16x8;
typedef __attribute__((ext_vector_type(4))) float f32x4;    // MFMA C/D frag

constexpr int TM = 8192;    // tokens (M)
constexpr int TK = 4096;    // in_features (K)
constexpr int TN = 16384;   // out_features (N)

#define BM 128
#define BN 128
#define BK 64

// fp32 -> bf16 round-to-nearest-even (inputs are finite normals; no NaN path needed)
__device__ __forceinline__ u16 f2bf(float f) {
  union { float f; unsigned int u; } v; v.f = f;
  unsigned int u = v.u;
  return (u16)((u + 0x7fffu + ((u >> 16) & 1u)) >> 16);
}

// async global->LDS, 16B per lane. LDS dest is wave-uniform base + lane*16,
// so l must be lane-contiguous in thread order (it is: j = i*256 + tid).
__device__ __forceinline__ void cp16_g2l(const u16* g, u16* l) {
  __builtin_amdgcn_global_load_lds(
      (const __attribute__((address_space(1))) unsigned int*)g,
      (__attribute__((address_space(3))) unsigned int*)l,
      16, 0, 0);
}

// ---------------- conversion pre-passes ----------------
__global__ __launch_bounds__(256) void cvt_x_kernel(const float* __restrict__ src,
                                                    u16* __restrict__ dst) {
  size_t i = ((size_t)blockIdx.x * 256 + threadIdx.x) * 8;
  float4 v0 = *(const float4*)(src + i);
  float4 v1 = *(const float4*)(src + i + 4);
  u16x8 o;
  o[0] = f2bf(v0.x); o[1] = f2bf(v0.y); o[2] = f2bf(v0.z); o[3] = f2bf(v0.w);
  o[4] = f2bf(v1.x); o[5] = f2bf(v1.y); o[6] = f2bf(v1.z); o[7] = f2bf(v1.w);
  *(u16x8*)(dst + i) = o;
}

__global__ __launch_bounds__(256) void cvt_w_kernel(const int* __restrict__ src,
                                                    u16* __restrict__ dst) {
  size_t i = ((size_t)blockIdx.x * 256 + threadIdx.x) * 8;
  int4 v0 = *(const int4*)(src + i);
  int4 v1 = *(const int4*)(src + i + 4);
  // |v| <= 127: exact in bf16
  u16x8 o;
  o[0] = f2bf((float)v0.x); o[1] = f2bf((float)v0.y); o[2] = f2bf((float)v0.z); o[3] = f2bf((float)v0.w);
  o[4] = f2bf((float)v1.x); o[5] = f2bf((float)v1.y); o[6] = f2bf((float)v1.z); o[7] = f2bf((float)v1.w);
  *(u16x8*)(dst + i) = o;
}

// ---------------- GEMM ----------------
// C[m][n] = scale * (sum_k x[m][k] * w[n][k] + bias[n])
// m97 structure: 128x128 tile, BK=64, 4 waves 2x2, each wave 4x4 of 16x16x32 MFMA.
// XOR chunk swizzle: LDS physical chunk p of row r holds global k-chunk (p ^ (r&7)).
template <bool FROM_WS>
__global__ __launch_bounds__(256) void qlinear_gemm(
    const u16* __restrict__ Abf, const u16* __restrict__ Bbf,
    const float* __restrict__ Xf, const int* __restrict__ Wq,
    const int* __restrict__ bias, const float* __restrict__ scalep,
    float* __restrict__ C) {
  __shared__ __attribute__((aligned(16))) u16 As[BM * BK];  // 16 KiB
  __shared__ __attribute__((aligned(16))) u16 Bs[BN * BK];  // 16 KiB

  const int t    = threadIdx.x;
  const int lane = t & 63;
  const int wv   = t >> 6;
  const int waveM = wv & 1;
  const int waveN = wv >> 1;

  // 16x16 block-window swizzle for LLC locality (locality-only; order-safe)
  const int bid   = (int)(blockIdx.y * gridDim.x + blockIdx.x);  // 0..8191
  const int win   = bid >> 8;        // 32 windows
  const int local = bid & 255;
  const int bxn   = (win & 7) * 16 + (local & 15);   // 0..127  (N blocks)
  const int byn   = (win >> 3) * 16 + (local >> 4);  // 0..63   (M blocks)
  const int bm = byn * BM;
  const int bn = bxn * BN;

  f32x4 acc[4][4];
#pragma unroll
  for (int i = 0; i < 4; i++)
#pragma unroll
    for (int j = 0; j < 4; j++) acc[i][j] = (f32x4){0.f, 0.f, 0.f, 0.f};

  for (int kt = 0; kt < TK; kt += BK) {
    __syncthreads();  // previous compute done reading LDS
#pragma unroll
    for (int i = 0; i < 4; i++) {
      const int j = i * 256 + t;       // chunk id 0..1023
      const int r = j >> 3;            // tile row 0..127
      const int g = (j & 7) ^ (r & 7); // global k-chunk this physical slot holds
      if constexpr (FROM_WS) {
        cp16_g2l(Abf + (size_t)(bm + r) * TK + kt + g * 8, As + (size_t)j * 8);
        cp16_g2l(Bbf + (size_t)(bn + r) * TK + kt + g * 8, Bs + (size_t)j * 8);
      } else {
        const float* xs = Xf + (size_t)(bm + r) * TK + kt + g * 8;
        float4 v0 = *(const float4*)xs;
        float4 v1 = *(const float4*)(xs + 4);
        u16x8 oa;
        oa[0] = f2bf(v0.x); oa[1] = f2bf(v0.y); oa[2] = f2bf(v0.z); oa[3] = f2bf(v0.w);
        oa[4] = f2bf(v1.x); oa[5] = f2bf(v1.y); oa[6] = f2bf(v1.z); oa[7] = f2bf(v1.w);
        *(u16x8*)(As + (size_t)j * 8) = oa;
        const int* wsrc = Wq + (size_t)(bn + r) * TK + kt + g * 8;
        int4 w0 = *(const int4*)wsrc;
        int4 w1 = *(const int4*)(wsrc + 4);
        u16x8 ob;
        ob[0] = f2bf((float)w0.x); ob[1] = f2bf((float)w0.y); ob[2] = f2bf((float)w0.z); ob[3] = f2bf((float)w0.w);
        ob[4] = f2bf((float)w1.x); ob[5] = f2bf((float)w1.y); ob[6] = f2bf((float)w1.z); ob[7] = f2bf((float)w1.w);
        *(u16x8*)(Bs + (size_t)j * 8) = ob;
      }
    }
    __syncthreads();  // drains vmcnt (compiler emits it) then barrier

#pragma unroll
    for (int kk = 0; kk < BK; kk += 32) {
      const int kq = (kk >> 3) + (lane >> 4);  // logical k-chunk 0..7
      const int px = kq ^ (lane & 7);          // physical chunk after swizzle
      bf16x8 af[4], bfr[4];
#pragma unroll
      for (int mi = 0; mi < 4; mi++) {
        const int r = waveM * 64 + mi * 16 + (lane & 15);
        af[mi] = *(const bf16x8*)(As + r * BK + px * 8);
      }
#pragma unroll
      for (int ni = 0; ni < 4; ni++) {
        const int r = waveN * 64 + ni * 16 + (lane & 15);
        bfr[ni] = *(const bf16x8*)(Bs + r * BK + px * 8);
      }
#pragma unroll
      for (int mi = 0; mi < 4; mi++)
#pragma unroll
        for (int ni = 0; ni < 4; ni++)
          acc[mi][ni] = __builtin_amdgcn_mfma_f32_16x16x32_bf16(af[mi], bfr[ni], acc[mi][ni], 0, 0, 0);
    }
  }

  // epilogue: C/D layout col = lane&15, row = (lane>>4)*4 + reg  [m89-verified]
  const float scale = scalep[0];
  const int row0 = bm + waveM * 64 + ((lane >> 4) << 2);
  const int col0 = bn + waveN * 64 + (lane & 15);
#pragma unroll
  for (int ni = 0; ni < 4; ni++) {
    const int gn = col0 + ni * 16;
    const float bsc = scale * (float)bias[gn];
#pragma unroll
    for (int mi = 0; mi < 4; mi++) {
      const int gm = row0 + mi * 16;
#pragma unroll
      for (int r = 0; r < 4; r++) {
        C[(size_t)(gm + r) * TN + gn] = scale * acc[mi][ni][r] + bsc;
      }
    }
  }
}

extern "C" void kernel_launch(void* const* d_in, const int* in_sizes, int n_in,
                              void* d_out, int out_size, void* d_ws, size_t ws_size,
                              hipStream_t stream) {
  const float* x      = (const float*)d_in[0];  // [8192, 4096] fp32
  const int*   w8     = (const int*)d_in[1];    // [16384, 4096] int32 in [-127,127]
  const int*   bias   = (const int*)d_in[2];    // [16384] int32
  const float* scalep = (const float*)d_in[3];  // [1] fp32
  float* out = (float*)d_out;                   // [8192, 16384] fp32

  const size_t xbf_bytes = (size_t)TM * TK * sizeof(u16);  //  64 MiB
  const size_t wbf_bytes = (size_t)TN * TK * sizeof(u16);  // 128 MiB

  dim3 grid(TN / BN, TM / BM);  // (128, 64)

  if (ws_size >= xbf_bytes + wbf_bytes) {
    u16* xbf = (u16*)d_ws;
    u16* wbf = (u16*)((char*)d_ws + xbf_bytes);
    cvt_x_kernel<<<(TM * TK) / 8 / 256, 256, 0, stream>>>(x, xbf);
    cvt_w_kernel<<<(TN * TK) / 8 / 256, 256, 0, stream>>>(w8, wbf);
    qlinear_gemm<true><<<grid, 256, 0, stream>>>(xbf, wbf, nullptr, nullptr, bias, scalep, out);
  } else {
    qlinear_gemm<false><<<grid, 256, 0, stream>>>(nullptr, nullptr, x, w8, bias, scalep, out);
  }
}